// Round 3
// baseline (323.187 us; speedup 1.0000x reference)
//
#include <hip/hip_runtime.h>

#define DI __device__ __forceinline__

typedef __attribute__((ext_vector_type(8))) __bf16 bf16x8;
typedef __attribute__((ext_vector_type(4))) float f32x4;
typedef __attribute__((ext_vector_type(8))) unsigned short ushort8;
typedef unsigned long long ull;

static DI unsigned short f2b(float f) {
  unsigned int x = __builtin_bit_cast(unsigned int, f);
  unsigned int r = (x + 0x7FFFu + ((x >> 16) & 1u)) >> 16;
  return (unsigned short)r;
}
static DI float b2f(unsigned short u) {
  return __builtin_bit_cast(float, (unsigned int)u << 16);
}
static DI float sigmf(float x) { return 1.0f / (1.0f + __expf(-x)); }

typedef const __attribute__((address_space(1))) void* gcptr;
typedef __attribute__((address_space(3))) void* lptr;
static DI void gl_lds16(const void* g, void* l) {
  __builtin_amdgcn_global_load_lds((gcptr)g, (lptr)l, 16, 0, 0);
}

// packed-C quad address (b64 units): rows 4*row4..4*row4+3, col c; NT = N/128
static DI size_t qaddr(int NT, int row4, int c) {
  int tm = row4 >> 5, tn = c >> 7;
  int rq = row4 & 31, c7 = c & 127;
  int wv = ((rq >> 4) << 1) | (c7 >> 6);
  int mf = (rq >> 2) & 3, nf = (c7 >> 4) & 3;
  int lane = ((rq & 3) << 4) | (c7 & 15);
  return ((size_t)(tm * NT + tn) << 12) + (size_t)((((wv << 4) + (mf << 2) + nf) << 6) + lane);
}

// ---------------- weight packing: B[k][n] -> Bp[k/8][n][k%8] (bf16) ----------
__global__ void prep_pack(const float* __restrict__ Wi, const float* __restrict__ Ui,
                          const float* __restrict__ bi, const float* __restrict__ Wf,
                          const float* __restrict__ Uf, const float* __restrict__ bfv,
                          const float* __restrict__ Wo, const float* __restrict__ Uo,
                          const float* __restrict__ bo, const float* __restrict__ Wu,
                          const float* __restrict__ Uu, const float* __restrict__ bu,
                          unsigned short* __restrict__ Wp, unsigned short* __restrict__ Upiou,
                          unsigned short* __restrict__ Upf, float* __restrict__ bias)
{
  int u = blockIdx.x * blockDim.x + threadIdx.x;  // 0..262143
  if (u < 131072) {            // Wp: [64][2048][8], cols = [Wi|Wf|Wo|Wu]
    int k8 = u >> 11, n = u & 2047;
    const float* W = (n < 512) ? Wi : (n < 1024) ? Wf : (n < 1536) ? Wo : Wu;
    int c = n & 511;
    ushort8 pk;
    #pragma unroll
    for (int t = 0; t < 8; ++t) pk[t] = f2b(W[(size_t)(k8*8+t)*512 + c]);
    *(ushort8*)&Wp[(size_t)u*8] = pk;
  } else if (u < 131072 + 98304) {  // Upiou: [64][1536][8], cols = [Ui|Uo|Uu]
    int v = u - 131072;
    int k8 = v / 1536, n = v - k8*1536;
    const float* U = (n < 512) ? Ui : (n < 1024) ? Uo : Uu;
    int c = n & 511;
    ushort8 pk;
    #pragma unroll
    for (int t = 0; t < 8; ++t) pk[t] = f2b(U[(size_t)(k8*8+t)*512 + c]);
    *(ushort8*)&Upiou[(size_t)v*8] = pk;
  } else {                     // Upf: [64][512][8]
    int v = u - 229376;
    int k8 = v >> 9, c = v & 511;
    ushort8 pk;
    #pragma unroll
    for (int t = 0; t < 8; ++t) pk[t] = f2b(Uf[(size_t)(k8*8+t)*512 + c]);
    *(ushort8*)&Upf[(size_t)v*8] = pk;
  }
  if (u < 2048) {
    bias[u] = (u < 512) ? bi[u] : (u < 1024) ? bfv[u-512] : (u < 1536) ? bo[u-1024] : bu[u-1536];
  }
}

// ---------------- gather emb rows -> X bf16 [22272][512] (level-padded) -----
__global__ void gather_x(const int* __restrict__ tok, const float* __restrict__ emb,
                         unsigned short* __restrict__ X)
{
  int u = blockIdx.x * blockDim.x + threadIdx.x;  // unit = 8 elems
  if (u >= 22272*64) return;
  int R = u >> 6, ch = u & 63;
  int l, node;
  if (R < 512)       { l = R >> 7; node = R & 127; int sz = 1 << (2*l); if (node >= sz) node = sz - 1; }
  else if (R < 768)  { l = 4; node = R - 512; }
  else if (R < 1792) { l = 5; node = R - 768; }
  else if (R < 5888) { l = 6; node = R - 1792; }
  else               { l = 7; node = R - 5888; }
  static const int offs_c[8] = {0,1,5,21,85,341,1365,5461};
  int tk = tok[offs_c[l] + node];
  const float* src = emb + (size_t)tk*512 + ch*8;
  ushort8 pk;
  #pragma unroll
  for (int t = 0; t < 8; ++t) pk[t] = f2b(src[t]);
  *(ushort8*)&X[(size_t)u*8] = pk;
}

// ---------------- zero-fill (replaces hipMemsetAsync) ------------------------
__global__ void fill_zero(f32x4* __restrict__ p, size_t n16)
{
  size_t i = (size_t)blockIdx.x * blockDim.x + threadIdx.x;
  size_t stride = (size_t)gridDim.x * blockDim.x;
  f32x4 z = {0.f, 0.f, 0.f, 0.f};
  for (; i < n16; i += stride) p[i] = z;
}

// ---------------- 256x256 8-wave 8-phase bf16 MFMA GEMM ----------------------
struct GDesc {
  const unsigned short* A;   // [M][512] bf16 row-major
  const unsigned short* Bp;  // packed [64][N][8]
  ull* C;                    // fragment-packed (qaddr) output
  int M, N, NT;              // NT = N/128
};

#define FENCE asm volatile("" ::: "memory")
#define SBAR  { FENCE; __builtin_amdgcn_s_barrier(); FENCE; }
#define VMCNT0 asm volatile("s_waitcnt vmcnt(0)" ::: "memory")

__global__ __launch_bounds__(512)
void gemm8p(GDesc g1, GDesc g2, int split, const float* __restrict__ bias)
{
  extern __shared__ unsigned short lds[];
  constexpr int ASZ = 256*64, BSZ = 8*256*8;   // elems (32KB each); lds = 2*(ASZ+BSZ)

  const int nwg = gridDim.x, orig = blockIdx.x;
  const int q = nwg >> 3, r = nwg & 7;
  const int xcd = orig & 7, idx = orig >> 3;
  const int wg = (xcd < r ? xcd*(q+1) : r*(q+1) + (xcd-r)*q) + idx;

  const bool role1 = (wg < split);
  GDesc g = role1 ? g1 : g2;
  const int lwg = role1 ? wg : wg - split;
  const int TN = g.N >> 8;
  const int tm = lwg / TN, tn = lwg - tm*TN;
  const int Mbase = tm << 8, Nbase = tn << 8;

  const int tid = threadIdx.x;
  const int wave = tid >> 6, lane = tid & 63;
  const int wr = wave >> 2, wc = wave & 3;

  const int lrow8 = lane >> 3;          // row within an 8-row staging group
  const int schunk = (lane & 7) ^ lrow8; // pre-swizzled source chunk

  f32x4 acc[8][4] = {};
  bf16x8 bfr[4][2];

  auto STAGE = [&](int t1, int p) {
    unsigned short* An = lds + p*ASZ;
    unsigned short* Bn = lds + 2*ASZ + p*BSZ;
    #pragma unroll
    for (int i = 0; i < 4; ++i) {
      int lrow = i*64 + wave*8 + lrow8;
      int grow = Mbase + lrow; if (grow >= g.M) grow = g.M - 1;
      gl_lds16(g.A + (size_t)grow*512 + t1*64 + schunk*8,
               An + (i*64 + wave*8)*64);
    }
    #pragma unroll
    for (int i = 0; i < 4; ++i) {
      int k8 = i*2 + (wave >> 2);
      int colb = (wave & 3)*64;
      gl_lds16(g.Bp + ((size_t)(t1*8 + k8)*g.N + Nbase + colb + lane)*8,
               Bn + (k8*256 + colb)*8);
    }
  };

  // per-phase macros (compile-time MQ so acc indices stay registers, rule #20)
  #define RDAF(MQ) { const unsigned short* Ab = lds + p*ASZ;                         \
    _Pragma("unroll") for (int m = 0; m < 2; ++m) {                                  \
      int row = wr*128 + ((MQ)*2+m)*16 + (lane & 15);                                \
      _Pragma("unroll") for (int ks = 0; ks < 2; ++ks) {                             \
        int kc = ks*4 + (lane >> 4);                                                 \
        af[m][ks] = *(const bf16x8*)&Ab[row*64 + ((kc ^ (row & 7)) * 8)];            \
      } } }
  #define RDBF() { const unsigned short* Bb = lds + 2*ASZ + p*BSZ;                   \
    _Pragma("unroll") for (int nf = 0; nf < 4; ++nf)                                 \
      _Pragma("unroll") for (int ks = 0; ks < 2; ++ks) {                             \
        int k8 = ks*4 + (lane >> 4);                                                 \
        bfr[nf][ks] = *(const bf16x8*)&Bb[(k8*256 + wc*64 + nf*16 + (lane & 15))*8]; \
      } }
  #define MMQ(MQ) { __builtin_amdgcn_s_setprio(1);                                   \
    _Pragma("unroll") for (int ks = 0; ks < 2; ++ks)                                 \
      _Pragma("unroll") for (int m = 0; m < 2; ++m)                                  \
        _Pragma("unroll") for (int nf = 0; nf < 4; ++nf)                             \
          acc[(MQ)*2+m][nf] = __builtin_amdgcn_mfma_f32_16x16x32_bf16(               \
              af[m][ks], bfr[nf][ks], acc[(MQ)*2+m][nf], 0, 0, 0);                   \
    __builtin_amdgcn_s_setprio(0); }

  STAGE(0, 0);
  VMCNT0;
  SBAR;
  for (int t = 0; t < 8; ++t) {
    const int p = t & 1;
    bf16x8 af[2][2];
    // phase 0: B-frags + A-quad 0, issue next tile's 8 staging loads
    RDBF(); RDAF(0);
    if (t < 7) STAGE(t+1, p^1);
    SBAR;
    MMQ(0);
    SBAR;
    // phases 1,2
    RDAF(1); SBAR; MMQ(1); SBAR;
    RDAF(2); SBAR; MMQ(2); SBAR;
    // phase 3: counted wait for next tile's loads at the very end
    RDAF(3);
    SBAR;
    MMQ(3);
    VMCNT0;
    SBAR;
  }

  // epilogue: packed b64 stores in qaddr format (+bias for role1)
  float bv[4];
  #pragma unroll
  for (int nf = 0; nf < 4; ++nf)
    bv[nf] = (bias != nullptr && role1) ? bias[Nbase + wc*64 + nf*16 + (lane & 15)] : 0.f;
  #pragma unroll
  for (int mf = 0; mf < 8; ++mf) {
    int row4 = ((Mbase + wr*128 + mf*16) >> 2) + (lane >> 4);
    #pragma unroll
    for (int nf = 0; nf < 4; ++nf) {
      int col = Nbase + wc*64 + nf*16 + (lane & 15);
      f32x4 a = acc[mf][nf];
      ull pk = (ull)f2b(a[0] + bv[nf]) | ((ull)f2b(a[1] + bv[nf]) << 16)
             | ((ull)f2b(a[2] + bv[nf]) << 32) | ((ull)f2b(a[3] + bv[nf]) << 48);
      g.C[qaddr(g.NT, row4, col)] = pk;
    }
  }
}

// ---------------- per-level elementwise combine (packed-C inputs) ------------
__global__ __launch_bounds__(256)
void combine2(const ull* __restrict__ Gq,   // packed, level-local, NT=16
              const ull* __restrict__ Rq,   // packed Riou, NT=12, or null
              const ull* __restrict__ Fq,   // packed Rf, NT=4, or null
              const float* __restrict__ cch,// children c [4n][512] or null
              float* __restrict__ hout,
              unsigned short* __restrict__ hbf,
              float* __restrict__ cout,
              unsigned short* __restrict__ htout,  // or null
              float* __restrict__ rootx,           // or null
              int n)
{
  const int b = blockIdx.x, t = threadIdx.x;
  #pragma unroll
  for (int half = 0; half < 2; ++half) {
    const int c = t + half * 256;
    ull gi4 = Gq[qaddr(16, b, c)];
    ull gf4 = Gq[qaddr(16, b, c + 512)];
    ull go4 = Gq[qaddr(16, b, c + 1024)];
    ull gu4 = Gq[qaddr(16, b, c + 1536)];
    ull ri4 = 0, ro4 = 0, ru4 = 0;
    if (Rq) {
      ri4 = Rq[qaddr(12, b, c)];
      ro4 = Rq[qaddr(12, b, c + 512)];
      ru4 = Rq[qaddr(12, b, c + 1024)];
    }
    float hts = 0.f;
    #pragma unroll
    for (int rI = 0; rI < 4; ++rI) {
      int j = b*4 + rI;
      float gi = b2f((unsigned short)(gi4 >> (16*rI)));
      float gf = b2f((unsigned short)(gf4 >> (16*rI)));
      float go = b2f((unsigned short)(go4 >> (16*rI)));
      float gu = b2f((unsigned short)(gu4 >> (16*rI)));
      float iv = sigmf(gi + b2f((unsigned short)(ri4 >> (16*rI))));
      float ov = sigmf(go + b2f((unsigned short)(ro4 >> (16*rI))));
      float uv = tanhf(gu + b2f((unsigned short)(ru4 >> (16*rI))));
      float fs = 0.f;
      if (Fq) {
        ull f4 = Fq[qaddr(4, j, c)];
        const float* cc = cch + (size_t)(j*4)*512 + c;
        #pragma unroll
        for (int k = 0; k < 4; ++k)
          fs += sigmf(gf + b2f((unsigned short)(f4 >> (16*k)))) * cc[(size_t)k*512];
      }
      float cv = iv*uv + fs;
      float hv = ov * tanhf(cv);
      if (j < n) {
        hout[(size_t)j*512 + c] = hv;
        hbf[(size_t)j*512 + c]  = f2b(hv);
        cout[(size_t)j*512 + c] = cv;
        if (rootx && j == 0) { rootx[c] = hv; rootx[512 + c] = cv; }
        hts += hv;
      }
    }
    if (htout) htout[(size_t)b*512 + c] = f2b(hts);
  }
}

// ---------------- launch -----------------------------------------------------
extern "C" void kernel_launch(void* const* d_in, const int* in_sizes, int n_in,
                              void* d_out, int out_size, void* d_ws, size_t ws_size,
                              hipStream_t stream)
{
  const int*   tok = (const int*)d_in[0];
  const float* emb = (const float*)d_in[1];
  const float* Wi  = (const float*)d_in[2];
  const float* Ui  = (const float*)d_in[3];
  const float* bi  = (const float*)d_in[4];
  const float* Wf  = (const float*)d_in[5];
  const float* Uf  = (const float*)d_in[6];
  const float* bfv = (const float*)d_in[7];
  const float* Wo  = (const float*)d_in[8];
  const float* Uo  = (const float*)d_in[9];
  const float* bo  = (const float*)d_in[10];
  const float* Wu  = (const float*)d_in[11];
  const float* Uu  = (const float*)d_in[12];
  const float* bu  = (const float*)d_in[13];

  char* ws = (char*)d_ws;
  unsigned short* Wp    = (unsigned short*)(ws + 0);           //  2,097,152
  unsigned short* Upiou = (unsigned short*)(ws + 2097152);     //  1,572,864
  unsigned short* Upf   = (unsigned short*)(ws + 3670016);     //    524,288
  float*          bias  = (float*)        (ws + 4194304);      //      8,192
  unsigned short* hbf   = (unsigned short*)(ws + 4202496);     // 22,369,280
  unsigned short* htbf  = (unsigned short*)(ws + 26571776);    //  5,592,064
  float*          cbuf  = (float*)        (ws + 32163840);     // 44,738,560
  ull*            RiouQ = (ull*)          (ws + 76902400);     // 12,582,912
  ull*            RfQ   = (ull*)          (ws + 89485312);     // 16,777,216

  char* ob = (char*)d_out;
  ull*            Gq = (ull*)ob;                               // 91,226,112 (packed, padded)
  unsigned short* X  = (unsigned short*)(ob + 91226112);       // 22,806,528
  float* fout = (float*)d_out;

  static const int  offs[9]    = {0,1,5,21,85,341,1365,5461,21845};
  static const int  padbase[8] = {0,128,256,384,512,768,1792,5888};
  static const long outoff[8]  = {87380,87376,87360,87296,87040,86016,81920,65536};

  prep_pack<<<1024, 256, 0, stream>>>(Wi,Ui,bi,Wf,Uf,bfv,Wo,Uo,bo,Wu,Uu,bu,
                                      Wp,Upiou,Upf,bias);
  gather_x<<<(22272*64)/256, 256, 0, stream>>>(tok, emb, X);

  GDesc gA { X, Wp, Gq, 22272, 2048, 16 };
  gemm8p<<<87*8, 512, 131072, stream>>>(gA, gA, 87*8, bias);

  // level 7: children are leaves (h=c=0)
  combine2<<<4096, 256, 0, stream>>>(Gq + (size_t)padbase[7]*512, nullptr, nullptr, nullptr,
      fout + (size_t)outoff[7]*512, hbf + (size_t)offs[7]*512, cbuf + (size_t)offs[7]*512,
      htbf + (size_t)offs[6]*512, nullptr, 16384);

  for (int l = 6; l >= 0; --l) {
    int n = 1 << (2*l);
    int tm1 = (n + 255) / 256, tm2 = (4*n + 255) / 256;
    int split = tm1 * 6;
    GDesc g1 { htbf + (size_t)offs[l]*512,   Upiou, RiouQ, n,   1536, 12 };
    GDesc g2 { hbf  + (size_t)offs[l+1]*512, Upf,   RfQ,   4*n, 512,  4  };
    gemm8p<<<split + tm2*2, 512, 131072, stream>>>(g1, g2, split, nullptr);
    combine2<<<(n + 3) / 4, 256, 0, stream>>>(
        Gq + (size_t)padbase[l]*512, RiouQ, RfQ, cbuf + (size_t)offs[l+1]*512,
        fout + (size_t)outoff[l]*512, hbf + (size_t)offs[l]*512, cbuf + (size_t)offs[l]*512,
        (l > 0) ? htbf + (size_t)offs[l-1]*512 : nullptr,
        (l == 0) ? fout + (size_t)87381*512 : nullptr,
        n);
  }

  // zero the leaf h region (erases the Gq/X scratch living there)
  fill_zero<<<2048, 256, 0, stream>>>((f32x4*)d_out, (size_t)65536*512*4/16);
}

// Round 4
// 259.665 us; speedup vs baseline: 1.2446x; 1.2446x over previous
//
#include <hip/hip_runtime.h>

#define DI __device__ __forceinline__

typedef __attribute__((ext_vector_type(8))) __bf16 bf16x8;
typedef __attribute__((ext_vector_type(4))) float f32x4;
typedef __attribute__((ext_vector_type(8))) unsigned short ushort8;
typedef unsigned long long ull;

static DI unsigned short f2b(float f) {
  unsigned int x = __builtin_bit_cast(unsigned int, f);
  unsigned int r = (x + 0x7FFFu + ((x >> 16) & 1u)) >> 16;
  return (unsigned short)r;
}
static DI float b2f(unsigned short u) {
  return __builtin_bit_cast(float, (unsigned int)u << 16);
}
static DI float sigmf(float x) { return 1.0f / (1.0f + __expf(-x)); }

typedef const __attribute__((address_space(1))) void* gcptr;
typedef __attribute__((address_space(3))) void* lptr;
static DI void gl_lds16(const void* g, void* l) {
  __builtin_amdgcn_global_load_lds((gcptr)g, (lptr)l, 16, 0, 0);
}

// gate-interleaved column: gate g, dim d -> raw col in [0,2048)
#define GCOL(g, d) ((((d) >> 5) << 7) + ((g) << 5) + ((d) & 31))

// packed-C quad address (b64 units): rows 4*row4..4*row4+3, col c; NT = N/128
static DI size_t qaddr(int NT, int row4, int c) {
  int tm = row4 >> 5, tn = c >> 7;
  int rq = row4 & 31, c7 = c & 127;
  int wv = ((rq >> 4) << 1) | (c7 >> 6);
  int mf = (rq >> 2) & 3, nf = (c7 >> 4) & 3;
  int lane = ((rq & 3) << 4) | (c7 & 15);
  return ((size_t)(tm * NT + tn) << 12) + (size_t)((((wv << 4) + (mf << 2) + nf) << 6) + lane);
}

// ---------------- weight packing ---------------------------------------------
// Wp: gate-interleaved cols. Upiou/Upf: block layout (unchanged).
__global__ void prep_pack(const float* __restrict__ Wi, const float* __restrict__ Ui,
                          const float* __restrict__ bi, const float* __restrict__ Wf,
                          const float* __restrict__ Uf, const float* __restrict__ bfv,
                          const float* __restrict__ Wo, const float* __restrict__ Uo,
                          const float* __restrict__ bo, const float* __restrict__ Wu,
                          const float* __restrict__ Uu, const float* __restrict__ bu,
                          unsigned short* __restrict__ Wp, unsigned short* __restrict__ Upiou,
                          unsigned short* __restrict__ Upf, float* __restrict__ bias)
{
  int u = blockIdx.x * blockDim.x + threadIdx.x;  // 0..262143
  if (u < 131072) {            // Wp: [64][2048][8], interleaved cols
    int k8 = u >> 11, n = u & 2047;
    int gate = (n >> 5) & 3;
    int d = ((n >> 7) << 5) | (n & 31);
    const float* W = (gate == 0) ? Wi : (gate == 1) ? Wf : (gate == 2) ? Wo : Wu;
    ushort8 pk;
    #pragma unroll
    for (int t = 0; t < 8; ++t) pk[t] = f2b(W[(size_t)(k8*8+t)*512 + d]);
    *(ushort8*)&Wp[(size_t)u*8] = pk;
  } else if (u < 131072 + 98304) {  // Upiou: [64][1536][8], cols = [Ui|Uo|Uu]
    int v = u - 131072;
    int k8 = v / 1536, n = v - k8*1536;
    const float* U = (n < 512) ? Ui : (n < 1024) ? Uo : Uu;
    int c = n & 511;
    ushort8 pk;
    #pragma unroll
    for (int t = 0; t < 8; ++t) pk[t] = f2b(U[(size_t)(k8*8+t)*512 + c]);
    *(ushort8*)&Upiou[(size_t)v*8] = pk;
  } else {                     // Upf: [64][512][8]
    int v = u - 229376;
    int k8 = v >> 9, c = v & 511;
    ushort8 pk;
    #pragma unroll
    for (int t = 0; t < 8; ++t) pk[t] = f2b(Uf[(size_t)(k8*8+t)*512 + c]);
    *(ushort8*)&Upf[(size_t)v*8] = pk;
  }
  if (u < 2048) {              // bias, interleaved to match Wp
    int gate = (u >> 5) & 3;
    int d = ((u >> 7) << 5) | (u & 31);
    bias[u] = (gate == 0) ? bi[d] : (gate == 1) ? bfv[d] : (gate == 2) ? bo[d] : bu[d];
  }
}

// ---------------- gather emb rows -> X bf16 [22272][512] (level-padded) -----
__global__ void gather_x(const int* __restrict__ tok, const float* __restrict__ emb,
                         unsigned short* __restrict__ X)
{
  int u = blockIdx.x * blockDim.x + threadIdx.x;  // unit = 8 elems
  if (u >= 22272*64) return;
  int R = u >> 6, ch = u & 63;
  int l, node;
  if (R < 512)       { l = R >> 7; node = R & 127; int sz = 1 << (2*l); if (node >= sz) node = sz - 1; }
  else if (R < 768)  { l = 4; node = R - 512; }
  else if (R < 1792) { l = 5; node = R - 768; }
  else if (R < 5888) { l = 6; node = R - 1792; }
  else               { l = 7; node = R - 5888; }
  static const int offs_c[8] = {0,1,5,21,85,341,1365,5461};
  int tk = tok[offs_c[l] + node];
  const float* src = emb + (size_t)tk*512 + ch*8;
  ushort8 pk;
  #pragma unroll
  for (int t = 0; t < 8; ++t) pk[t] = f2b(src[t]);
  *(ushort8*)&X[(size_t)u*8] = pk;
}

// ---------------- bf16 MFMA GEMM (2-phase dbuf, 128x128, 4 waves) ------------
struct GDesc {
  const unsigned short* A;   // [M][512] bf16 row-major
  const unsigned short* Bp;  // packed [64][N][8]
  ull* C;                    // fragment-packed (qaddr) output
  int M, N, NT;              // NT = N/128
};
struct L7P {                 // fused level-7 outputs (FUSED only)
  float* hout; unsigned short* hb; float* cb; unsigned short* ht;
  float* zbase; size_t z4;   // leaf zero region (f32x4 units)
};

template<bool FUSED>
__global__ __launch_bounds__(256)
void gemm512(GDesc g1, GDesc g2, int split, const float* __restrict__ bias, L7P l7)
{
  __shared__ float smemf[128*132];   // 67.6 KB: staging (64KB) / f32 exchange
  unsigned short* As = (unsigned short*)smemf;            // [2][128*64]
  unsigned short* Bs = (unsigned short*)smemf + 2*128*64; // [2][8*128*8]

  const int nwg = gridDim.x, orig = blockIdx.x;
  const int q = nwg >> 3, r = nwg & 7;
  const int xcd = orig & 7, idx = orig >> 3;
  const int wg = (xcd < r ? xcd*(q+1) : r*(q+1) + (xcd-r)*q) + idx;

  const bool role1 = (wg < split);
  GDesc g = role1 ? g1 : g2;
  const int lwg = role1 ? wg : wg - split;
  const int tm = lwg / g.NT, tn = lwg - tm * g.NT;

  const int tid = threadIdx.x;
  const int wave = tid >> 6, lane = tid & 63;
  const int Mbase = tm * 128, Nbase = tn * 128;
  const int wr = wave >> 1, wc = wave & 1;

  const int arow_l = wave*8 + (lane >> 3);
  const int acol8  = lane & 7;
  const int sw8    = arow_l & 7;

  f32x4 acc[4][4] = {};

  auto STAGE = [&](int p, int k0) {
    #pragma unroll
    for (int c = 0; c < 4; ++c) {
      int grow = Mbase + c*32 + arow_l;
      if (grow >= g.M) grow = g.M - 1;
      gl_lds16(g.A + (size_t)grow*512 + k0 + ((acol8 ^ sw8) * 8),
               As + p*(128*64) + (c*32 + wave*8)*64);
    }
    #pragma unroll
    for (int c = 0; c < 4; ++c) {
      int k8 = c*2 + (wave >> 1);
      int colh = (wave & 1) * 64;
      gl_lds16(g.Bp + ((size_t)((k0 >> 3) + k8) * g.N + Nbase + colh + lane) * 8,
               Bs + p*(8*128*8) + (k8*128 + colh)*8);
    }
  };

  auto COMPUTE = [&](int p) {
    #pragma unroll
    for (int ks = 0; ks < 2; ++ks) {
      bf16x8 af[4], bfr[4];
      #pragma unroll
      for (int mf = 0; mf < 4; ++mf) {
        int row = wr*64 + mf*16 + (lane & 15);
        int kc  = ks*4 + (lane >> 4);
        af[mf] = *(const bf16x8*)&As[p*(128*64) + row*64 + ((kc ^ (row & 7)) * 8)];
      }
      #pragma unroll
      for (int nf = 0; nf < 4; ++nf) {
        int col = wc*64 + nf*16 + (lane & 15);
        int k8  = ks*4 + (lane >> 4);
        bfr[nf] = *(const bf16x8*)&Bs[p*(8*128*8) + (k8*128 + col) * 8];
      }
      #pragma unroll
      for (int mf = 0; mf < 4; ++mf)
        #pragma unroll
        for (int nf = 0; nf < 4; ++nf)
          acc[mf][nf] = __builtin_amdgcn_mfma_f32_16x16x32_bf16(af[mf], bfr[nf], acc[mf][nf], 0, 0, 0);
    }
  };

  STAGE(0, 0);
  __syncthreads();
  #pragma unroll
  for (int it = 0; it < 7; ++it) {
    STAGE((it + 1) & 1, (it + 1) * 64);
    COMPUTE(it & 1);
    __syncthreads();
  }
  COMPUTE(1);

  auto ZERO_DUTY = [&]() {
    if constexpr (FUSED) {
      size_t b4 = (size_t)orig * 3072;
      f32x4 z = {0.f, 0.f, 0.f, 0.f};
      f32x4* zp = (f32x4*)l7.zbase;
      #pragma unroll
      for (int i = 0; i < 12; ++i) {
        size_t off = b4 + (size_t)i*256 + tid;
        if (off < l7.z4) zp[off] = z;
      }
    }
  };

  if (FUSED && tm >= 46) {
    // ---- fused level-7 combine (children are leaves: c = i*u, h = o*tanh(c))
    __syncthreads();                      // protect staging LDS before reuse
    #pragma unroll
    for (int mf = 0; mf < 4; ++mf) {
      int rbase = wr*64 + mf*16 + (lane >> 4)*4;
      #pragma unroll
      for (int nf = 0; nf < 4; ++nf) {
        int col = wc*64 + nf*16 + (lane & 15);
        #pragma unroll
        for (int rr = 0; rr < 4; ++rr)
          smemf[(rbase + rr)*132 + col] = acc[mf][nf][rr];
      }
    }
    __syncthreads();
    ZERO_DUTY();                          // overlaps with combine below
    const int dlow = tid & 31, rowg = tid >> 5;    // rowg 0..7
    const int d = tn*32 + dlow;
    const float bi_ = bias[tn*128      + dlow];
    const float bo_ = bias[tn*128 + 64 + dlow];
    const float bu_ = bias[tn*128 + 96 + dlow];
    const int nodebase = Mbase - 5888 + rowg*16;
    float hts = 0.f;
    #pragma unroll
    for (int rr = 0; rr < 16; ++rr) {
      int lrow = rowg*16 + rr;
      float gi = smemf[lrow*132      + dlow];
      float go = smemf[lrow*132 + 64 + dlow];
      float gu = smemf[lrow*132 + 96 + dlow];
      float iv = sigmf(gi + bi_), ov = sigmf(go + bo_), uv = tanhf(gu + bu_);
      float cv = iv * uv;
      float hv = ov * tanhf(cv);
      size_t node = nodebase + rr;
      l7.hout[node*512 + d] = hv;
      l7.hb[node*512 + d]   = f2b(hv);
      l7.cb[node*512 + d]   = cv;
      hts += hv;
      if ((rr & 3) == 3) {
        l7.ht[(size_t)((nodebase + rr - 3) >> 2)*512 + d] = f2b(hts);
        hts = 0.f;
      }
    }
  } else {
    ZERO_DUTY();
    // ---- packed b64 G/R stores (+bias for role1 when bias given)
    float bv[4];
    #pragma unroll
    for (int nf = 0; nf < 4; ++nf)
      bv[nf] = (bias != nullptr && role1) ? bias[Nbase + wc*64 + nf*16 + (lane & 15)] : 0.f;
    ull* Cb = g.C + ((size_t)(tm * g.NT + tn) << 12) + ((size_t)wave << 10);
    #pragma unroll
    for (int mf = 0; mf < 4; ++mf)
      #pragma unroll
      for (int nf = 0; nf < 4; ++nf) {
        f32x4 a = acc[mf][nf];
        ull pk = (ull)f2b(a[0] + bv[nf]) | ((ull)f2b(a[1] + bv[nf]) << 16)
               | ((ull)f2b(a[2] + bv[nf]) << 32) | ((ull)f2b(a[3] + bv[nf]) << 48);
        Cb[(mf*4 + nf)*64 + lane] = pk;
      }
  }
}

// ---------------- per-level elementwise combine (packed-C inputs) ------------
__global__ __launch_bounds__(256)
void combine2(const ull* __restrict__ Gq,   // packed, gate-interleaved cols, NT=16
              const ull* __restrict__ Rq,   // packed Riou, NT=12
              const ull* __restrict__ Fq,   // packed Rf, NT=4
              const float* __restrict__ cch,// children c [4n][512]
              float* __restrict__ hout,
              unsigned short* __restrict__ hbf,
              float* __restrict__ cout,
              unsigned short* __restrict__ htout,  // or null
              float* __restrict__ rootx,           // or null
              int n)
{
  const int b = blockIdx.x, t = threadIdx.x;
  #pragma unroll
  for (int half = 0; half < 2; ++half) {
    const int c = t + half * 256;
    ull gi4 = Gq[qaddr(16, b, GCOL(0, c))];
    ull gf4 = Gq[qaddr(16, b, GCOL(1, c))];
    ull go4 = Gq[qaddr(16, b, GCOL(2, c))];
    ull gu4 = Gq[qaddr(16, b, GCOL(3, c))];
    ull ri4 = Rq[qaddr(12, b, c)];
    ull ro4 = Rq[qaddr(12, b, c + 512)];
    ull ru4 = Rq[qaddr(12, b, c + 1024)];
    float hts = 0.f;
    #pragma unroll
    for (int rI = 0; rI < 4; ++rI) {
      int j = b*4 + rI;
      float gi = b2f((unsigned short)(gi4 >> (16*rI)));
      float gf = b2f((unsigned short)(gf4 >> (16*rI)));
      float go = b2f((unsigned short)(go4 >> (16*rI)));
      float gu = b2f((unsigned short)(gu4 >> (16*rI)));
      float iv = sigmf(gi + b2f((unsigned short)(ri4 >> (16*rI))));
      float ov = sigmf(go + b2f((unsigned short)(ro4 >> (16*rI))));
      float uv = tanhf(gu + b2f((unsigned short)(ru4 >> (16*rI))));
      ull f4 = Fq[qaddr(4, j, c)];
      const float* cc = cch + (size_t)(j*4)*512 + c;
      float fs = 0.f;
      #pragma unroll
      for (int k = 0; k < 4; ++k)
        fs += sigmf(gf + b2f((unsigned short)(f4 >> (16*k)))) * cc[(size_t)k*512];
      float cv = iv*uv + fs;
      float hv = ov * tanhf(cv);
      if (j < n) {
        hout[(size_t)j*512 + c] = hv;
        hbf[(size_t)j*512 + c]  = f2b(hv);
        cout[(size_t)j*512 + c] = cv;
        if (rootx && j == 0) { rootx[c] = hv; rootx[512 + c] = cv; }
        hts += hv;
      }
    }
    if (htout) htout[(size_t)b*512 + c] = f2b(hts);
  }
}

// ---------------- launch -----------------------------------------------------
extern "C" void kernel_launch(void* const* d_in, const int* in_sizes, int n_in,
                              void* d_out, int out_size, void* d_ws, size_t ws_size,
                              hipStream_t stream)
{
  const int*   tok = (const int*)d_in[0];
  const float* emb = (const float*)d_in[1];
  const float* Wi  = (const float*)d_in[2];
  const float* Ui  = (const float*)d_in[3];
  const float* bi  = (const float*)d_in[4];
  const float* Wf  = (const float*)d_in[5];
  const float* Uf  = (const float*)d_in[6];
  const float* bfv = (const float*)d_in[7];
  const float* Wo  = (const float*)d_in[8];
  const float* Uo  = (const float*)d_in[9];
  const float* bo  = (const float*)d_in[10];
  const float* Wu  = (const float*)d_in[11];
  const float* Uu  = (const float*)d_in[12];
  const float* bu  = (const float*)d_in[13];

  char* ws = (char*)d_ws;
  unsigned short* Wp    = (unsigned short*)(ws + 0);           //  2,097,152
  unsigned short* Upiou = (unsigned short*)(ws + 2097152);     //  1,572,864
  unsigned short* Upf   = (unsigned short*)(ws + 3670016);     //    524,288
  float*          bias  = (float*)        (ws + 4194304);      //      8,192
  unsigned short* hbf   = (unsigned short*)(ws + 4202496);     // 22,369,280
  unsigned short* htbf  = (unsigned short*)(ws + 26571776);    //  5,592,064
  float*          cbuf  = (float*)        (ws + 32163840);     // 44,738,560
  ull*            RiouQ = (ull*)          (ws + 76902400);     // 12,582,912
  ull*            RfQ   = (ull*)          (ws + 89485312);     // 16,777,216
  ull*            Gq    = (ull*)          (ws + 106262528);    // 24,117,248 (46 row-tiles)
  unsigned short* X     = (unsigned short*)(ws + 130379776);   // 22,806,528 -> 153,186,304

  float* fout = (float*)d_out;

  static const int  offs[9]    = {0,1,5,21,85,341,1365,5461,21845};
  static const int  padbase[8] = {0,128,256,384,512,768,1792,5888};
  static const long outoff[8]  = {87380,87376,87360,87296,87040,86016,81920,65536};

  prep_pack<<<1024, 256, 0, stream>>>(Wi,Ui,bi,Wf,Uf,bfv,Wo,Uo,bo,Wu,Uu,bu,
                                      Wp,Upiou,Upf,bias);
  gather_x<<<(22272*64)/256, 256, 0, stream>>>(tok, emb, X);

  // big GEMM: gates for all internal nodes; fused level-7 combine + leaf zeros
  GDesc gA { X, Wp, Gq, 22272, 2048, 16 };
  L7P l7 { fout + (size_t)outoff[7]*512, hbf + (size_t)offs[7]*512,
           cbuf + (size_t)offs[7]*512, htbf + (size_t)offs[6]*512,
           fout, (size_t)65536*512/4 };
  gemm512<true><<<174*16, 256, 0, stream>>>(gA, gA, 174*16, bias, l7);

  L7P l7n {};
  for (int l = 6; l >= 0; --l) {
    int n = 1 << (2*l);
    int tm1 = (n + 127) / 128, tm2 = (4*n + 127) / 128;
    int split = tm1 * 12;
    GDesc g1 { htbf + (size_t)offs[l]*512,   Upiou, RiouQ, n,   1536, 12 };
    GDesc g2 { hbf  + (size_t)offs[l+1]*512, Upf,   RfQ,   4*n, 512,  4  };
    gemm512<false><<<split + tm2*4, 256, 0, stream>>>(g1, g2, split, nullptr, l7n);
    combine2<<<(n + 3) / 4, 256, 0, stream>>>(
        Gq + (size_t)padbase[l]*512, RiouQ, RfQ, cbuf + (size_t)offs[l+1]*512,
        fout + (size_t)outoff[l]*512, hbf + (size_t)offs[l]*512, cbuf + (size_t)offs[l]*512,
        (l > 0) ? htbf + (size_t)offs[l-1]*512 : nullptr,
        (l == 0) ? fout + (size_t)87381*512 : nullptr,
        n);
  }
}